// Round 2
// baseline (3104.184 us; speedup 1.0000x reference)
//
#include <hip/hip_runtime.h>
#include <hip/hip_fp16.h>
#include <cstdint>
#include <cstddef>

#define NN 10000
#define NE 320000
#define TT 24
#define HD 64
#define G4 256   // 4*H
// feature layout: [n][hf][ch][12] halfs; per node-half block = 64*12 halfs = 1536 B
#define NODE_HALFS (2*HD*12)

__device__ __forceinline__ float sigm(float x){ return 1.0f/(1.0f + __expf(-x)); }
__device__ __forceinline__ float tanh_fast(float x){ return 2.0f/(1.0f + __expf(-2.0f*x)) - 1.0f; }

__device__ __forceinline__ float2 h2f2(unsigned int u){
  __half2 h = *reinterpret_cast<const __half2*>(&u);
  return __half22float2(h);
}
__device__ __forceinline__ unsigned int f2h2(float a, float b){
  __half2 h = __floats2half2_rn(a, b);
  return *reinterpret_cast<unsigned int*>(&h);
}

// ---- setup: degrees ----
__global__ __launch_bounds__(256) void degree_kernel(const int* __restrict__ esrc, const int* __restrict__ edst,
                                                     int* __restrict__ deg_out, int* __restrict__ deg_in){
  int e = blockIdx.x*256 + threadIdx.x;
  if (e < NE){
    atomicAdd(&deg_out[esrc[e]], 1);
    atomicAdd(&deg_in[edst[e]], 1);
  }
}

// ---- setup: symmetric norms ----
__global__ __launch_bounds__(256) void norm_kernel(const int* __restrict__ deg_out, const int* __restrict__ deg_in,
                                                   float* __restrict__ norm_src, float* __restrict__ norm_dst){
  int i = blockIdx.x*256 + threadIdx.x;
  if (i < NN){
    int a = deg_out[i]; norm_src[i] = (a>0) ? rsqrtf((float)a) : 0.0f;
    int b = deg_in[i];  norm_dst[i] = (b>0) ? rsqrtf((float)b) : 0.0f;
  }
}

// ---- setup: exclusive prefix sum over in-degrees (single block) ----
__global__ __launch_bounds__(256) void scan_kernel(const int* __restrict__ deg_in, int* __restrict__ csr_off,
                                                   int* __restrict__ cursor){
  __shared__ int sums[256];
  const int CH = (NN + 255)/256;
  int tid = threadIdx.x;
  int beg = tid*CH; if (beg > NN) beg = NN;
  int end = beg+CH; if (end > NN) end = NN;
  int s = 0;
  for (int i=beg;i<end;i++) s += deg_in[i];
  sums[tid] = s;
  __syncthreads();
  if (tid == 0){
    int run = 0;
    for (int i=0;i<256;i++){ int v = sums[i]; sums[i] = run; run += v; }
  }
  __syncthreads();
  int run = sums[tid];
  for (int i=beg;i<end;i++){ csr_off[i] = run; cursor[i] = run; run += deg_in[i]; }
  if (tid == 0) csr_off[NN] = NE;
}

// ---- setup: CSR fill (counting sort by dst), pack (src, norm_src[src]) as int2 ----
__global__ __launch_bounds__(256) void fill_kernel(const int* __restrict__ esrc, const int* __restrict__ edst,
                                                   int* __restrict__ cursor, int2* __restrict__ csr_pk,
                                                   const float* __restrict__ norm_src){
  int e = blockIdx.x*256 + threadIdx.x;
  if (e < NE){
    int d = edst[e]; int s = esrc[e];
    int pos = atomicAdd(&cursor[d], 1);
    csr_pk[pos] = make_int2(s, __float_as_int(norm_src[s]));
  }
}

// ---- phase A: per-node LSTM, weights in registers; writes h_all fp16 [n][hf][ch][12] ----
__global__ __launch_bounds__(256) void lstm_kernel(const float* __restrict__ blob, const float* __restrict__ W_ih,
                                                   const float* __restrict__ b_ih, const float* __restrict__ W_hh,
                                                   const float* __restrict__ b_hh, __half* __restrict__ h_all){
  const int n = blockIdx.x;
  const int g = threadIdx.x;
  __shared__ float lh[HD];
  __shared__ float lg[G4];

  float4 w4[16];
  const float4* wp = reinterpret_cast<const float4*>(W_hh + (size_t)n*(G4*HD) + (size_t)g*HD);
  #pragma unroll
  for (int i=0;i<16;i++) w4[i] = wp[i];

  const float wx = W_ih[(size_t)n*G4 + g];
  const float bs = b_ih[(size_t)n*G4 + g] + b_hh[(size_t)n*G4 + g];

  float c = 0.0f;
  float hprev = 0.0f;
  unsigned int hb[12];   // 12 packed half2 t-pairs (statically indexed under full unroll)
  if (g < HD) lh[g] = 0.0f;
  __syncthreads();

  #pragma unroll
  for (int t=0;t<TT;t++){
    float xt = blob[n*TT + t];
    float gate = fmaf(wx, xt, bs);
    const float4* h4 = reinterpret_cast<const float4*>(lh);
    #pragma unroll
    for (int i=0;i<16;i++){
      float4 hv = h4[i];
      gate = fmaf(hv.x, w4[i].x, gate);
      gate = fmaf(hv.y, w4[i].y, gate);
      gate = fmaf(hv.z, w4[i].z, gate);
      gate = fmaf(hv.w, w4[i].w, gate);
    }
    lg[g] = gate;
    __syncthreads();
    if (g < HD){
      float iv = sigm(lg[g]);
      float fv = sigm(lg[HD+g]);
      float gv = tanh_fast(lg[2*HD+g]);
      float ov = sigm(lg[3*HD+g]);
      c = fmaf(fv, c, iv*gv);
      float h = ov * tanh_fast(c);
      lh[g] = h;
      if (t & 1) hb[t>>1] = f2h2(hprev, h);
      else       hprev = h;
    }
    __syncthreads();
  }
  if (g < HD){
    #pragma unroll
    for (int hf=0; hf<2; hf++){
      uint2* dst = reinterpret_cast<uint2*>(h_all + ((size_t)(n*2+hf)*HD + g)*12);
      #pragma unroll
      for (int m=0; m<3; m++){
        uint2 s; s.x = hb[hf*6 + 2*m]; s.y = hb[hf*6 + 2*m + 1];
        dst[m] = s;
      }
    }
  }
}

// ---- phase B: gconv layer. wave per (node, t-half). lane = channel.
// Gather: 3x uint2 contiguous per edge per lane. Epilogue: k-outer shfl GEMV with on-the-fly Wg loads.
__global__ __launch_bounds__(256, 8) void gconv_mid_kernel(const __half* __restrict__ src_feat, __half* __restrict__ dst_feat,
                                                        const float* __restrict__ Wg, const float* __restrict__ bg,
                                                        const int* __restrict__ csr_off, const int2* __restrict__ csr_pk,
                                                        const float* __restrict__ norm_dst){
  int wid = blockIdx.x*4 + (threadIdx.x >> 6);
  int lane = threadIdx.x & 63;
  if (wid >= NN*2) return;
  int n  = wid >> 1;
  int hf = wid & 1;
  const size_t lane_off = ((size_t)hf*HD + lane)*12;   // halfs

  float2 acc[6];
  #pragma unroll
  for (int j=0;j<6;j++) acc[j] = make_float2(0.f, 0.f);

  int e = csr_off[n];
  const int end = csr_off[n+1];
  for (; e+1 < end; e += 2){
    int2 p0 = csr_pk[e];
    int2 p1 = csr_pk[e+1];
    float w0 = __int_as_float(p0.y);
    float w1 = __int_as_float(p1.y);
    const uint2* b0 = reinterpret_cast<const uint2*>(src_feat + (size_t)p0.x*NODE_HALFS + lane_off);
    const uint2* b1 = reinterpret_cast<const uint2*>(src_feat + (size_t)p1.x*NODE_HALFS + lane_off);
    uint2 u0[3], u1[3];
    #pragma unroll
    for (int m=0;m<3;m++) u0[m] = b0[m];
    #pragma unroll
    for (int m=0;m<3;m++) u1[m] = b1[m];
    #pragma unroll
    for (int m=0;m<3;m++){
      float2 f0a = h2f2(u0[m].x), f0b = h2f2(u0[m].y);
      float2 f1a = h2f2(u1[m].x), f1b = h2f2(u1[m].y);
      acc[2*m].x   = fmaf(w0, f0a.x, acc[2*m].x);
      acc[2*m].y   = fmaf(w0, f0a.y, acc[2*m].y);
      acc[2*m+1].x = fmaf(w0, f0b.x, acc[2*m+1].x);
      acc[2*m+1].y = fmaf(w0, f0b.y, acc[2*m+1].y);
      acc[2*m].x   = fmaf(w1, f1a.x, acc[2*m].x);
      acc[2*m].y   = fmaf(w1, f1a.y, acc[2*m].y);
      acc[2*m+1].x = fmaf(w1, f1b.x, acc[2*m+1].x);
      acc[2*m+1].y = fmaf(w1, f1b.y, acc[2*m+1].y);
    }
  }
  if (e < end){
    int2 p0 = csr_pk[e];
    float w0 = __int_as_float(p0.y);
    const uint2* b0 = reinterpret_cast<const uint2*>(src_feat + (size_t)p0.x*NODE_HALFS + lane_off);
    uint2 u0[3];
    #pragma unroll
    for (int m=0;m<3;m++) u0[m] = b0[m];
    #pragma unroll
    for (int m=0;m<3;m++){
      float2 f0a = h2f2(u0[m].x), f0b = h2f2(u0[m].y);
      acc[2*m].x   = fmaf(w0, f0a.x, acc[2*m].x);
      acc[2*m].y   = fmaf(w0, f0a.y, acc[2*m].y);
      acc[2*m+1].x = fmaf(w0, f0b.x, acc[2*m+1].x);
      acc[2*m+1].y = fmaf(w0, f0b.y, acc[2*m+1].y);
    }
  }
  float nd = norm_dst[n];
  #pragma unroll
  for (int j=0;j<6;j++){ acc[j].x *= nd; acc[j].y *= nd; }

  float bias = bg[lane];
  float oe[6], oo[6];
  #pragma unroll
  for (int j=0;j<6;j++){ oe[j] = bias; oo[j] = bias; }
  #pragma unroll
  for (int k=0;k<HD;k++){
    float wk = Wg[k*HD + lane];
    #pragma unroll
    for (int j=0;j<6;j++){
      oe[j] = fmaf(__shfl(acc[j].x, k, 64), wk, oe[j]);
      oo[j] = fmaf(__shfl(acc[j].y, k, 64), wk, oo[j]);
    }
  }
  uint2* dst = reinterpret_cast<uint2*>(dst_feat + (size_t)n*NODE_HALFS + lane_off);
  #pragma unroll
  for (int m=0;m<3;m++){
    uint2 s;
    s.x = f2h2(fmaxf(oe[2*m],   0.0f), fmaxf(oo[2*m],   0.0f));
    s.y = f2h2(fmaxf(oe[2*m+1], 0.0f), fmaxf(oo[2*m+1], 0.0f));
    dst[m] = s;
  }
}

// ---- phase B: last hidden gconv fused with 64->1 projection ----
__global__ __launch_bounds__(256, 8) void gconv_last_kernel(const __half* __restrict__ src_feat, float* __restrict__ q,
                                                         const float* __restrict__ Wg, const float* __restrict__ bg,
                                                         const float* __restrict__ Wg2,
                                                         const int* __restrict__ csr_off, const int2* __restrict__ csr_pk,
                                                         const float* __restrict__ norm_dst, const float* __restrict__ norm_src){
  int wid = blockIdx.x*4 + (threadIdx.x >> 6);
  int lane = threadIdx.x & 63;
  if (wid >= NN*2) return;
  int n  = wid >> 1;
  int hf = wid & 1;
  const size_t lane_off = ((size_t)hf*HD + lane)*12;   // halfs

  float2 acc[6];
  #pragma unroll
  for (int j=0;j<6;j++) acc[j] = make_float2(0.f, 0.f);

  int e = csr_off[n];
  const int end = csr_off[n+1];
  for (; e+1 < end; e += 2){
    int2 p0 = csr_pk[e];
    int2 p1 = csr_pk[e+1];
    float w0 = __int_as_float(p0.y);
    float w1 = __int_as_float(p1.y);
    const uint2* b0 = reinterpret_cast<const uint2*>(src_feat + (size_t)p0.x*NODE_HALFS + lane_off);
    const uint2* b1 = reinterpret_cast<const uint2*>(src_feat + (size_t)p1.x*NODE_HALFS + lane_off);
    uint2 u0[3], u1[3];
    #pragma unroll
    for (int m=0;m<3;m++) u0[m] = b0[m];
    #pragma unroll
    for (int m=0;m<3;m++) u1[m] = b1[m];
    #pragma unroll
    for (int m=0;m<3;m++){
      float2 f0a = h2f2(u0[m].x), f0b = h2f2(u0[m].y);
      float2 f1a = h2f2(u1[m].x), f1b = h2f2(u1[m].y);
      acc[2*m].x   = fmaf(w0, f0a.x, acc[2*m].x);
      acc[2*m].y   = fmaf(w0, f0a.y, acc[2*m].y);
      acc[2*m+1].x = fmaf(w0, f0b.x, acc[2*m+1].x);
      acc[2*m+1].y = fmaf(w0, f0b.y, acc[2*m+1].y);
      acc[2*m].x   = fmaf(w1, f1a.x, acc[2*m].x);
      acc[2*m].y   = fmaf(w1, f1a.y, acc[2*m].y);
      acc[2*m+1].x = fmaf(w1, f1b.x, acc[2*m+1].x);
      acc[2*m+1].y = fmaf(w1, f1b.y, acc[2*m+1].y);
    }
  }
  if (e < end){
    int2 p0 = csr_pk[e];
    float w0 = __int_as_float(p0.y);
    const uint2* b0 = reinterpret_cast<const uint2*>(src_feat + (size_t)p0.x*NODE_HALFS + lane_off);
    uint2 u0[3];
    #pragma unroll
    for (int m=0;m<3;m++) u0[m] = b0[m];
    #pragma unroll
    for (int m=0;m<3;m++){
      float2 f0a = h2f2(u0[m].x), f0b = h2f2(u0[m].y);
      acc[2*m].x   = fmaf(w0, f0a.x, acc[2*m].x);
      acc[2*m].y   = fmaf(w0, f0a.y, acc[2*m].y);
      acc[2*m+1].x = fmaf(w0, f0b.x, acc[2*m+1].x);
      acc[2*m+1].y = fmaf(w0, f0b.y, acc[2*m+1].y);
    }
  }
  float nd = norm_dst[n];
  #pragma unroll
  for (int j=0;j<6;j++){ acc[j].x *= nd; acc[j].y *= nd; }

  float bias = bg[lane];
  float w2v = Wg2[lane];
  float oe[6], oo[6];
  #pragma unroll
  for (int j=0;j<6;j++){ oe[j] = bias; oo[j] = bias; }
  #pragma unroll
  for (int k=0;k<HD;k++){
    float wk = Wg[k*HD + lane];
    #pragma unroll
    for (int j=0;j<6;j++){
      oe[j] = fmaf(__shfl(acc[j].x, k, 64), wk, oe[j]);
      oo[j] = fmaf(__shfl(acc[j].y, k, 64), wk, oo[j]);
    }
  }
  float ns = norm_src[n];
  #pragma unroll
  for (int j=0;j<6;j++){
    float se = fmaxf(oe[j], 0.0f) * w2v;
    float so = fmaxf(oo[j], 0.0f) * w2v;
    #pragma unroll
    for (int off=32; off; off >>= 1){
      se += __shfl_xor(se, off, 64);
      so += __shfl_xor(so, off, 64);
    }
    if (lane == 0){
      q[n*32 + hf*12 + 2*j]     = se * ns;
      q[n*32 + hf*12 + 2*j + 1] = so * ns;
    }
  }
}

// ---- phase B: final scalar aggregation -> output (N,T). Full wave: 2 edges/iter via halves ----
__global__ __launch_bounds__(256) void out_kernel(const float* __restrict__ q, const int* __restrict__ csr_off,
                                                  const int2* __restrict__ csr_pk, const float* __restrict__ norm_dst,
                                                  const float* __restrict__ bg2, float* __restrict__ out){
  int n = blockIdx.x*4 + (threadIdx.x >> 6);
  int lane = threadIdx.x & 63;
  if (n >= NN) return;
  int sub = lane >> 5;        // 0: even edge, 1: odd edge
  int tl  = lane & 31;        // timestep (0..23 active)
  bool act = tl < TT;
  int e = csr_off[n];
  const int end = csr_off[n+1];
  float s0 = 0.f, s1 = 0.f;
  for (; e+3 < end; e += 4){
    int a = csr_pk[e+sub].x;
    int b = csr_pk[e+2+sub].x;
    if (act){
      s0 += q[a*32 + tl];
      s1 += q[b*32 + tl];
    }
  }
  for (; e+1 < end; e += 2){
    int a = csr_pk[e+sub].x;
    if (act) s0 += q[a*32 + tl];
  }
  if (e < end && sub == 0 && act) s1 += q[csr_pk[e].x*32 + tl];
  float s = s0 + s1;
  s += __shfl_xor(s, 32, 64);
  if (sub == 0 && act) out[n*TT + tl] = fmaf(norm_dst[n], s, bg2[0]);
}

extern "C" void kernel_launch(void* const* d_in, const int* in_sizes, int n_in,
                              void* d_out, int out_size, void* d_ws, size_t ws_size,
                              hipStream_t stream) {
  (void)in_sizes; (void)n_in; (void)out_size; (void)ws_size;
  const float* blob  = (const float*)d_in[0];
  const float* W_ih  = (const float*)d_in[1];
  const float* b_ih  = (const float*)d_in[2];
  const float* W_hh  = (const float*)d_in[3];
  const float* b_hh  = (const float*)d_in[4];
  const float* Wg0   = (const float*)d_in[5];
  const float* bg0   = (const float*)d_in[6];
  const float* Wg1   = (const float*)d_in[7];
  const float* bg1   = (const float*)d_in[8];
  const float* Wg2   = (const float*)d_in[9];
  const float* bg2   = (const float*)d_in[10];
  const int* edge_src = (const int*)d_in[11];
  const int* edge_dst = (const int*)d_in[12];
  float* out = (float*)d_out;

  char* ws = (char*)d_ws;
  size_t off = 0;
  auto alloc = [&](size_t bytes)->char* {
    char* p = ws + off; off += (bytes + 255) & ~(size_t)255; return p;
  };
  __half* h_all   = (__half*)alloc((size_t)NN*TT*HD*sizeof(__half));  // 30.7 MB, [n][hf][ch][12]
  __half* z1      = (__half*)alloc((size_t)NN*TT*HD*sizeof(__half));  // 30.7 MB
  float*  q       = (float*) alloc((size_t)NN*32*sizeof(float));      // 1.28 MB
  int*    deg_out = (int*)   alloc((size_t)NN*sizeof(int));
  int*    deg_in  = (int*)   alloc((size_t)NN*sizeof(int));
  float*  norm_src= (float*) alloc((size_t)NN*sizeof(float));
  float*  norm_dst= (float*) alloc((size_t)NN*sizeof(float));
  int*    csr_off = (int*)   alloc((size_t)(NN+1)*sizeof(int));
  int*    cursor  = (int*)   alloc((size_t)NN*sizeof(int));
  int2*   csr_pk  = (int2*)  alloc((size_t)NE*sizeof(int2));          // 2.56 MB

  hipMemsetAsync(deg_out, 0, (size_t)NN*sizeof(int), stream);
  hipMemsetAsync(deg_in,  0, (size_t)NN*sizeof(int), stream);

  degree_kernel<<<(NE+255)/256, 256, 0, stream>>>(edge_src, edge_dst, deg_out, deg_in);
  norm_kernel<<<(NN+255)/256, 256, 0, stream>>>(deg_out, deg_in, norm_src, norm_dst);
  scan_kernel<<<1, 256, 0, stream>>>(deg_in, csr_off, cursor);
  fill_kernel<<<(NE+255)/256, 256, 0, stream>>>(edge_src, edge_dst, cursor, csr_pk, norm_src);

  lstm_kernel<<<NN, 256, 0, stream>>>(blob, W_ih, b_ih, W_hh, b_hh, h_all);

  gconv_mid_kernel<<<(NN*2)/4, 256, 0, stream>>>(h_all, z1, Wg0, bg0, csr_off, csr_pk, norm_dst);
  gconv_last_kernel<<<(NN*2)/4, 256, 0, stream>>>(z1, q, Wg1, bg1, Wg2, csr_off, csr_pk, norm_dst, norm_src);
  out_kernel<<<(NN+3)/4, 256, 0, stream>>>(q, csr_off, csr_pk, norm_dst, bg2, out);
}